// Round 1
// baseline (328.936 us; speedup 1.0000x reference)
//
#include <hip/hip_runtime.h>
#include <math.h>

#define Bn   128
#define Rn   1152
#define CIn  8
#define Cn   10
#define On   16
#define BO   2048      // Bn*On
#define CBO  20480     // Cn*BO
#define RCH  16        // r rows per chunk
#define XSTR 132       // LDS row stride (floats) per b row: 16r*8i=128 + 4 pad
#define WSTR 132       // LDS row stride per o row: 128 + 4 pad

// Thread map (256 threads): bits 0-1 = rr (4), bits 2-3 = og (4), bits 4-7 = bq (16)
// Thread owns b = bh*64 + bq + 16*j (j<4), o = og + 4*m (m<4), r = 4*k + rr (k<4).
// Grid: 1440 = Cn * 72 chunks * 2 b-halves.

template<int PASS>
__global__ __launch_bounds__(256, 2)
void pass_kernel(const float* __restrict__ X, const float* __restrict__ Wt,
                 const float* __restrict__ Sprev, const float* __restrict__ N2,
                 float* __restrict__ Tc, float* __restrict__ Lc)
{
    __shared__ float xs[64 * XSTR];   // 33.8 KB
    __shared__ float wsh[On * WSTR];  //  8.4 KB

    const int blk   = blockIdx.x;
    const int c     = blk / 144;
    const int rem   = blk - c * 144;
    const int chunk = rem >> 1;
    const int bh    = rem & 1;
    const int r0    = chunk * RCH;

    const int tid = threadIdx.x;
    const int rr  = tid & 3;
    const int og  = (tid >> 2) & 3;
    const int bq  = tid >> 4;

    // ---- stage x[bh*64 .. +63][r0..r0+15][0..7] -> xs[bl][r*8+i], stride XSTR
    {
        const float* xbase = X + (size_t)(bh * 64) * (Rn * CIn) + (size_t)r0 * CIn;
        #pragma unroll
        for (int l = tid; l < 2048; l += 256) {            // 2048 float4
            const int bl  = l >> 5;                        // 32 f4 per b row
            const int off = (l & 31) << 2;
            const float4 v = *(const float4*)(xbase + (size_t)bl * (Rn * CIn) + off);
            *(float4*)(xs + bl * XSTR + off) = v;
        }
    }
    // ---- stage W[c][r0..+15][i][o] -> wsh[o][r*8+i] (transposed), stride WSTR
    {
        const float* wbase = Wt + (size_t)c * (Rn * CIn * On) + (size_t)r0 * (CIn * On);
        #pragma unroll
        for (int l = tid; l < 512; l += 256) {             // 512 float4
            const int rl = l >> 5;
            const int i  = (l >> 2) & 7;
            const int o4 = (l & 3) << 2;
            const float4 v = *(const float4*)(wbase + rl * 128 + i * On + o4);
            wsh[(o4 + 0) * WSTR + rl * 8 + i] = v.x;
            wsh[(o4 + 1) * WSTR + rl * 8 + i] = v.y;
            wsh[(o4 + 2) * WSTR + rl * 8 + i] = v.z;
            wsh[(o4 + 3) * WSTR + rl * 8 + i] = v.w;
        }
    }

    // ---- per-thread Vsum (pre-scaled by log2e), from previous passes' S and N2
    float vs[4][4];
    if (PASS > 1) {
        float coef[PASS];  // only PASS-1 used
        #pragma unroll
        for (int t = 0; t < PASS - 1; ++t) {
            const float n2 = N2[t];
            coef[t] = n2 / ((1.0f + n2) * sqrtf(n2)) * 1.4426950408889634f;
        }
        #pragma unroll
        for (int j = 0; j < 4; ++j) {
            const int b = bh * 64 + bq + 16 * j;
            #pragma unroll
            for (int m = 0; m < 4; ++m) {
                const int o   = og + 4 * m;
                const int idx = c * BO + b * On + o;
                float a = 0.0f;
                #pragma unroll
                for (int t = 0; t < PASS - 1; ++t)
                    a = fmaf(coef[t], Sprev[t * CBO + idx], a);
                vs[j][m] = a;
            }
        }
    }

    __syncthreads();

    float tacc[4][4], lacc[4][4];
    #pragma unroll
    for (int j = 0; j < 4; ++j)
        #pragma unroll
        for (int m = 0; m < 4; ++m) { tacc[j][m] = 0.0f; lacc[j][m] = 0.0f; }

    #pragma unroll
    for (int k = 0; k < 4; ++k) {
        const int r = (k << 2) | rr;
        float4 xa[4], xb[4];
        #pragma unroll
        for (int j = 0; j < 4; ++j) {
            const float* p = xs + (bq + 16 * j) * XSTR + r * 8;
            xa[j] = *(const float4*)p;
            xb[j] = *(const float4*)(p + 4);
        }
        float4 wa[4], wb[4];
        #pragma unroll
        for (int m = 0; m < 4; ++m) {
            const float* q = wsh + (og + 4 * m) * WSTR + r * 8;
            wa[m] = *(const float4*)q;
            wb[m] = *(const float4*)(q + 4);
        }
        #pragma unroll
        for (int j = 0; j < 4; ++j) {
            #pragma unroll
            for (int m = 0; m < 4; ++m) {
                float u = xa[j].x * wa[m].x;
                u = fmaf(xa[j].y, wa[m].y, u);
                u = fmaf(xa[j].z, wa[m].z, u);
                u = fmaf(xa[j].w, wa[m].w, u);
                u = fmaf(xb[j].x, wb[m].x, u);
                u = fmaf(xb[j].y, wb[m].y, u);
                u = fmaf(xb[j].z, wb[m].z, u);
                u = fmaf(xb[j].w, wb[m].w, u);
                if (PASS == 1) {
                    tacc[j][m] += u;
                } else {
                    const float e = exp2f(u * vs[j][m]);
                    lacc[j][m] += e;
                    tacc[j][m] = fmaf(e, u, tacc[j][m]);
                }
            }
        }
    }

    // ---- reduce over rr (lane bits 0-1, in-wave) and atomically accumulate
    #pragma unroll
    for (int j = 0; j < 4; ++j) {
        const int b = bh * 64 + bq + 16 * j;
        #pragma unroll
        for (int m = 0; m < 4; ++m) {
            const int o = og + 4 * m;
            float tv = tacc[j][m];
            tv += __shfl_xor(tv, 1);
            tv += __shfl_xor(tv, 2);
            float lv = 16.0f;                 // PASS 1: exp(0)=1, 16 r's per (b,o) per wg
            if (PASS > 1) {
                lv = lacc[j][m];
                lv += __shfl_xor(lv, 1);
                lv += __shfl_xor(lv, 2);
            }
            if (rr == 0) {
                const int idx = c * BO + b * On + o;
                atomicAdd(&Tc[idx], tv);
                atomicAdd(&Lc[idx], lv);
            }
        }
    }
}

// s = T/L; store into S slot; zero T/L for next pass; reduce sum(s^2) -> N2 slot
__global__ __launch_bounds__(256)
void combine_kernel(float* __restrict__ Tc, float* __restrict__ Lc,
                    float* __restrict__ Sout, float* __restrict__ n2out)
{
    const int i = blockIdx.x * 256 + threadIdx.x;   // 80 blocks * 256 = 20480
    const float s = Tc[i] / Lc[i];
    Sout[i] = s;
    Tc[i] = 0.0f;
    Lc[i] = 0.0f;
    float sq = s * s;
    #pragma unroll
    for (int d = 1; d < 64; d <<= 1) sq += __shfl_xor(sq, d);
    __shared__ float red[4];
    if ((threadIdx.x & 63) == 0) red[threadIdx.x >> 6] = sq;
    __syncthreads();
    if (threadIdx.x == 0)
        atomicAdd(n2out, red[0] + red[1] + red[2] + red[3]);
}

__global__ __launch_bounds__(256)
void final_kernel(const float* __restrict__ S, const float* __restrict__ n2p,
                  float* __restrict__ out)
{
    const int i = blockIdx.x * 256 + threadIdx.x;
    const float n2 = *n2p;
    const float coef = n2 / ((1.0f + n2) * sqrtf(n2));
    out[i] = coef * S[i];
}

extern "C" void kernel_launch(void* const* d_in, const int* in_sizes, int n_in,
                              void* d_out, int out_size, void* d_ws, size_t ws_size,
                              hipStream_t stream)
{
    const float* X  = (const float*)d_in[0];
    const float* Wt = (const float*)d_in[1];
    float* ws = (float*)d_ws;
    float* Tc = ws;                  // 20480
    float* Lc = ws + CBO;            // 20480
    float* N2 = ws + 2 * CBO;        // 3 (+1 pad)
    float* S  = ws + 2 * CBO + 4;    // 3 * 20480

    // zero atomic accumulators (T, L, N2); ws is poisoned 0xAA before each launch
    hipMemsetAsync(ws, 0, (size_t)(2 * CBO + 4) * sizeof(float), stream);

    pass_kernel<1><<<1440, 256, 0, stream>>>(X, Wt, S, N2, Tc, Lc);
    combine_kernel<<<80, 256, 0, stream>>>(Tc, Lc, S + 0 * CBO, N2 + 0);
    pass_kernel<2><<<1440, 256, 0, stream>>>(X, Wt, S, N2, Tc, Lc);
    combine_kernel<<<80, 256, 0, stream>>>(Tc, Lc, S + 1 * CBO, N2 + 1);
    pass_kernel<3><<<1440, 256, 0, stream>>>(X, Wt, S, N2, Tc, Lc);
    combine_kernel<<<80, 256, 0, stream>>>(Tc, Lc, S + 2 * CBO, N2 + 2);
    final_kernel<<<80, 256, 0, stream>>>(S + 2 * CBO, N2 + 2, (float*)d_out);
}

// Round 2
// 135.102 us; speedup vs baseline: 2.4347x; 2.4347x over previous
//
#include <hip/hip_runtime.h>
#include <math.h>

#define Bn   128
#define Rn   1152
#define CIn  8
#define Cn   10
#define On   16
#define BO   2048      // Bn*On
#define CBO  20480     // Cn*BO
#define NSEG 18        // r-segments; each segment = 64 r = 4 chunks of 16
#define XSTR 132       // LDS row stride (floats): 16r*8i=128 + 4 pad
#define WSTR 132

// Thread map (256 threads): bits0-1 = rr(4), bits2-3 = og(4), bits4-7 = bq(16)
// wg owns: c, b-tile of 32 (b = b0 + bq + 16j, j<2), o = og + 4m (m<4),
//          r-segment of 64 (4 chunks of 16; r_local = k*4 + rr, k<4)
// Grid: 720 = Cn(10) * 4 b-tiles * NSEG(18)

template<int PASS>
__global__ __launch_bounds__(256, 2)
void pass_kernel(const float* __restrict__ X, const float* __restrict__ Wt,
                 const float* __restrict__ Sprev, const float* __restrict__ N2,
                 float* __restrict__ PT, float* __restrict__ PL)
{
    __shared__ float xs[32 * XSTR];   // 16.9 KB
    __shared__ float wsh[On * WSTR];  //  8.4 KB

    const int blk = blockIdx.x;
    const int c   = blk / 72;
    const int rem = blk - c * 72;
    const int bt  = rem / 18;
    const int seg = rem - bt * 18;
    const int b0  = bt * 32;
    const int rs0 = seg * 64;

    const int tid = threadIdx.x;
    const int rr  = tid & 3;
    const int og  = (tid >> 2) & 3;
    const int bq  = tid >> 4;

    // ---- per-thread Vsum (pre-scaled by log2e) from previous passes
    float vs[2][4];
    if (PASS > 1) {
        float coef[PASS];
        #pragma unroll
        for (int t = 0; t < PASS - 1; ++t) {
            const float n2 = N2[t];
            coef[t] = n2 / ((1.0f + n2) * sqrtf(n2)) * 1.4426950408889634f;
        }
        #pragma unroll
        for (int j = 0; j < 2; ++j) {
            const int b = b0 + bq + 16 * j;
            #pragma unroll
            for (int m = 0; m < 4; ++m) {
                const int idx = c * BO + b * On + (og + 4 * m);
                float a = 0.0f;
                #pragma unroll
                for (int t = 0; t < PASS - 1; ++t)
                    a = fmaf(coef[t], Sprev[t * CBO + idx], a);
                vs[j][m] = a;
            }
        }
    }

    float tacc[2][4], lacc[2][4];
    #pragma unroll
    for (int j = 0; j < 2; ++j)
        #pragma unroll
        for (int m = 0; m < 4; ++m) { tacc[j][m] = 0.0f; lacc[j][m] = 0.0f; }

    for (int ch = 0; ch < 4; ++ch) {
        const int r0 = rs0 + ch * 16;

        // stage x[b0..b0+31][r0..r0+15][0..7] -> xs[bl][rl*8+i]
        {
            const float* xbase = X + (size_t)b0 * (Rn * CIn) + (size_t)r0 * CIn;
            #pragma unroll
            for (int l = tid; l < 1024; l += 256) {        // 1024 float4
                const int bl  = l >> 5;
                const int off = (l & 31) << 2;
                const float4 v = *(const float4*)(xbase + (size_t)bl * (Rn * CIn) + off);
                *(float4*)(xs + bl * XSTR + off) = v;
            }
        }
        // stage W[c][r0..r0+15][i][o] -> wsh[o][rl*8+i] (transposed)
        {
            const float* wbase = Wt + (size_t)c * (Rn * CIn * On) + (size_t)r0 * (CIn * On);
            #pragma unroll
            for (int l = tid; l < 512; l += 256) {         // 512 float4
                const int rl = l >> 5;
                const int i  = (l >> 2) & 7;
                const int o4 = (l & 3) << 2;
                const float4 v = *(const float4*)(wbase + rl * 128 + i * On + o4);
                wsh[(o4 + 0) * WSTR + rl * 8 + i] = v.x;
                wsh[(o4 + 1) * WSTR + rl * 8 + i] = v.y;
                wsh[(o4 + 2) * WSTR + rl * 8 + i] = v.z;
                wsh[(o4 + 3) * WSTR + rl * 8 + i] = v.w;
            }
        }
        __syncthreads();

        #pragma unroll
        for (int k = 0; k < 4; ++k) {
            const int r = (k << 2) | rr;
            float4 xa[2], xb[2];
            #pragma unroll
            for (int j = 0; j < 2; ++j) {
                const float* p = xs + (bq + 16 * j) * XSTR + r * 8;
                xa[j] = *(const float4*)p;
                xb[j] = *(const float4*)(p + 4);
            }
            float4 wa[4], wb[4];
            #pragma unroll
            for (int m = 0; m < 4; ++m) {
                const float* q = wsh + (og + 4 * m) * WSTR + r * 8;
                wa[m] = *(const float4*)q;
                wb[m] = *(const float4*)(q + 4);
            }
            #pragma unroll
            for (int j = 0; j < 2; ++j) {
                #pragma unroll
                for (int m = 0; m < 4; ++m) {
                    float u = xa[j].x * wa[m].x;
                    u = fmaf(xa[j].y, wa[m].y, u);
                    u = fmaf(xa[j].z, wa[m].z, u);
                    u = fmaf(xa[j].w, wa[m].w, u);
                    u = fmaf(xb[j].x, wb[m].x, u);
                    u = fmaf(xb[j].y, wb[m].y, u);
                    u = fmaf(xb[j].z, wb[m].z, u);
                    u = fmaf(xb[j].w, wb[m].w, u);
                    if (PASS == 1) {
                        tacc[j][m] += u;
                    } else {
                        const float e = exp2f(u * vs[j][m]);
                        lacc[j][m] += e;
                        tacc[j][m] = fmaf(e, u, tacc[j][m]);
                    }
                }
            }
        }
        __syncthreads();
    }

    // ---- reduce over rr (lane bits 0-1) and store segment partials (no atomics)
    #pragma unroll
    for (int j = 0; j < 2; ++j) {
        const int b = b0 + bq + 16 * j;
        #pragma unroll
        for (int m = 0; m < 4; ++m) {
            float tv = tacc[j][m];
            tv += __shfl_xor(tv, 1);
            tv += __shfl_xor(tv, 2);
            float lv = 0.0f;
            if (PASS > 1) {
                lv = lacc[j][m];
                lv += __shfl_xor(lv, 1);
                lv += __shfl_xor(lv, 2);
            }
            if (rr == 0) {
                const int idx = seg * CBO + c * BO + b * On + (og + 4 * m);
                PT[idx] = tv;
                if (PASS > 1) PL[idx] = lv;
            }
        }
    }
}

// sum partials over NSEG segs; s = T/L; store S slot; reduce sum(s^2) -> N2 slot
template<int PASS>
__global__ __launch_bounds__(256)
void combine_kernel(const float* __restrict__ PT, const float* __restrict__ PL,
                    float* __restrict__ Sout, float* __restrict__ n2out)
{
    const int i = blockIdx.x * 256 + threadIdx.x;   // 80 blocks * 256 = 20480
    float T = 0.0f, L = 0.0f;
    #pragma unroll
    for (int s = 0; s < NSEG; ++s) T += PT[s * CBO + i];
    if (PASS == 1) {
        L = (float)Rn;   // exp(0)=1 summed over all r
    } else {
        #pragma unroll
        for (int s = 0; s < NSEG; ++s) L += PL[s * CBO + i];
    }
    const float sv = T / L;
    Sout[i] = sv;
    float sq = sv * sv;
    #pragma unroll
    for (int d = 1; d < 64; d <<= 1) sq += __shfl_xor(sq, d);
    __shared__ float red[4];
    if ((threadIdx.x & 63) == 0) red[threadIdx.x >> 6] = sq;
    __syncthreads();
    if (threadIdx.x == 0)
        atomicAdd(n2out, red[0] + red[1] + red[2] + red[3]);
}

__global__ __launch_bounds__(256)
void final_kernel(const float* __restrict__ S, const float* __restrict__ n2p,
                  float* __restrict__ out)
{
    const int i = blockIdx.x * 256 + threadIdx.x;
    const float n2 = *n2p;
    const float coef = n2 / ((1.0f + n2) * sqrtf(n2));
    out[i] = coef * S[i];
}

extern "C" void kernel_launch(void* const* d_in, const int* in_sizes, int n_in,
                              void* d_out, int out_size, void* d_ws, size_t ws_size,
                              hipStream_t stream)
{
    const float* X  = (const float*)d_in[0];
    const float* Wt = (const float*)d_in[1];
    float* ws = (float*)d_ws;
    float* N2 = ws;                          // 4 floats (3 used)
    float* PT = ws + 4;                      // NSEG*CBO = 368640
    float* PL = PT + NSEG * CBO;             // NSEG*CBO
    float* S  = PL + NSEG * CBO;             // 3*CBO

    // only N2 needs zeroing (partials are fully overwritten every pass)
    hipMemsetAsync(ws, 0, 16, stream);

    pass_kernel<1><<<720, 256, 0, stream>>>(X, Wt, S, N2, PT, PL);
    combine_kernel<1><<<80, 256, 0, stream>>>(PT, PL, S + 0 * CBO, N2 + 0);
    pass_kernel<2><<<720, 256, 0, stream>>>(X, Wt, S, N2, PT, PL);
    combine_kernel<2><<<80, 256, 0, stream>>>(PT, PL, S + 1 * CBO, N2 + 1);
    pass_kernel<3><<<720, 256, 0, stream>>>(X, Wt, S, N2, PT, PL);
    combine_kernel<3><<<80, 256, 0, stream>>>(PT, PL, S + 2 * CBO, N2 + 2);
    final_kernel<<<80, 256, 0, stream>>>(S + 2 * CBO, N2 + 2, (float*)d_out);
}

// Round 3
// 124.534 us; speedup vs baseline: 2.6413x; 1.0849x over previous
//
#include <hip/hip_runtime.h>
#include <math.h>

#define Bn   128
#define Rn   1152
#define CIn  8
#define Cn   10
#define On   16
#define BO   2048      // Bn*On
#define CBO  20480     // Cn*BO
#define RC   12        // r's per wave-segment
#define NSEG 96        // 96*12 = 1152
#define PSEG 24        // wg-level partial segments (4 waves reduced per wg)

// ---- transpose x[b][r][i] -> XT[r][g][b][q]  (i = g*4+q), float4 units
__global__ __launch_bounds__(256)
void transpose_x(const float* __restrict__ X, float* __restrict__ XT)
{
    const int r = blockIdx.x;
    const int b = threadIdx.x & 127;
    const int g = threadIdx.x >> 7;
    float4 v = *(const float4*)(X + (size_t)b * (Rn * CIn) + r * CIn + g * 4);
    ((float4*)XT)[r * 256 + g * 128 + b] = v;
}

// ---- pass kernel: wave-autonomous, no LDS in main loop
// wg(256) = 4 waves; wave w of block blk covers (c, bh, seg = segq*4+w)
// lane = local b (0..63); thread owns all 16 o's.
// Grid: 480 = Cn(10) * 2 bh * 24 segq
template<int PASS>
__global__ __launch_bounds__(256, 2)
void pass_kernel(const float* __restrict__ XT, const float* __restrict__ W,
                 const float* __restrict__ Sprev, const float* __restrict__ N2,
                 float* __restrict__ PT, float* __restrict__ PL)
{
    __shared__ float red[4][64][34];   // padded stride 34 -> 34.8 KB

    const int blk  = blockIdx.x;
    const int c    = blk / 48;
    const int rem  = blk - c * 48;
    const int bh   = rem / 24;
    const int segq = rem - bh * 24;
    const int tid  = threadIdx.x;
    const int w    = tid >> 6;
    const int lane = tid & 63;
    const int b    = bh * 64 + lane;
    const int r0   = __builtin_amdgcn_readfirstlane((segq * 4 + w) * RC);

    // per-thread Vsum (pre-scaled by log2e) from previous passes
    float vs[16];
    if (PASS > 1) {
        float coef[PASS];
        #pragma unroll
        for (int t = 0; t < PASS - 1; ++t) {
            const float n2 = N2[t];
            coef[t] = n2 / ((1.0f + n2) * sqrtf(n2)) * 1.4426950408889634f;
        }
        const float* sp = Sprev + c * BO + b * On;
        #pragma unroll
        for (int q = 0; q < 4; ++q) {
            float4 a = make_float4(0.f, 0.f, 0.f, 0.f);
            #pragma unroll
            for (int t = 0; t < PASS - 1; ++t) {
                const float4 s4 = *(const float4*)(sp + t * CBO + q * 4);
                a.x = fmaf(coef[t], s4.x, a.x);
                a.y = fmaf(coef[t], s4.y, a.y);
                a.z = fmaf(coef[t], s4.z, a.z);
                a.w = fmaf(coef[t], s4.w, a.w);
            }
            vs[q * 4 + 0] = a.x; vs[q * 4 + 1] = a.y;
            vs[q * 4 + 2] = a.z; vs[q * 4 + 3] = a.w;
        }
    }

    float tacc[16], lacc[16];
    #pragma unroll
    for (int o = 0; o < 16; ++o) { tacc[o] = 0.0f; lacc[o] = 0.0f; }

    const float4* XT4 = (const float4*)XT;
    for (int rr = 0; rr < RC; ++rr) {
        const int r = r0 + rr;
        const float4 xa = XT4[r * 256 + b];
        const float4 xb = XT4[r * 256 + 128 + b];
        // wave-uniform W block: 128 contiguous floats -> scalar loads
        const int woff = __builtin_amdgcn_readfirstlane((c * Rn + r) * 128);
        const float* wr = W + woff;
        #pragma unroll
        for (int o = 0; o < 16; ++o) {
            float u = xa.x * wr[o];
            u = fmaf(xa.y, wr[16 + o], u);
            u = fmaf(xa.z, wr[32 + o], u);
            u = fmaf(xa.w, wr[48 + o], u);
            u = fmaf(xb.x, wr[64 + o], u);
            u = fmaf(xb.y, wr[80 + o], u);
            u = fmaf(xb.z, wr[96 + o], u);
            u = fmaf(xb.w, wr[112 + o], u);
            if (PASS == 1) {
                tacc[o] += u;
            } else {
                const float e = exp2f(u * vs[o]);
                lacc[o] += e;
                tacc[o] = fmaf(e, u, tacc[o]);
            }
        }
    }

    // wg-level reduce across the 4 waves (4 segs) -> one partial per wg
    #pragma unroll
    for (int o = 0; o < 16; ++o) {
        red[w][lane][o]      = tacc[o];
        red[w][lane][16 + o] = lacc[o];
    }
    __syncthreads();

    {
        const int bl = tid >> 2;          // 0..63
        const int og = tid & 3;           // 0..3
        const int bg = bh * 64 + bl;
        float4 tv, lv;
        float* tp = (float*)&tv;
        float* lp = (float*)&lv;
        #pragma unroll
        for (int q = 0; q < 4; ++q) {
            const int o = og * 4 + q;
            tp[q] = red[0][bl][o] + red[1][bl][o] + red[2][bl][o] + red[3][bl][o];
            lp[q] = red[0][bl][16 + o] + red[1][bl][16 + o] +
                    red[2][bl][16 + o] + red[3][bl][16 + o];
        }
        const int idx = segq * CBO + c * BO + bg * On + og * 4;
        *(float4*)(PT + idx) = tv;
        if (PASS > 1) *(float4*)(PL + idx) = lv;
    }
}

// sum partials over PSEG segs; s = T/L; store S slot; reduce sum(s^2) -> N2 slot
template<int PASS>
__global__ __launch_bounds__(256)
void combine_kernel(const float* __restrict__ PT, const float* __restrict__ PL,
                    float* __restrict__ Sout, float* __restrict__ n2out)
{
    const int i = blockIdx.x * 256 + threadIdx.x;   // 80 blocks * 256 = 20480
    float T = 0.0f, L = 0.0f;
    #pragma unroll
    for (int s = 0; s < PSEG; ++s) T += PT[s * CBO + i];
    if (PASS == 1) {
        L = (float)Rn;
    } else {
        #pragma unroll
        for (int s = 0; s < PSEG; ++s) L += PL[s * CBO + i];
    }
    const float sv = T / L;
    Sout[i] = sv;
    float sq = sv * sv;
    #pragma unroll
    for (int d = 1; d < 64; d <<= 1) sq += __shfl_xor(sq, d);
    __shared__ float red[4];
    if ((threadIdx.x & 63) == 0) red[threadIdx.x >> 6] = sq;
    __syncthreads();
    if (threadIdx.x == 0)
        atomicAdd(n2out, red[0] + red[1] + red[2] + red[3]);
}

__global__ __launch_bounds__(256)
void final_kernel(const float* __restrict__ S, const float* __restrict__ n2p,
                  float* __restrict__ out)
{
    const int i = blockIdx.x * 256 + threadIdx.x;
    const float n2 = *n2p;
    const float coef = n2 / ((1.0f + n2) * sqrtf(n2));
    out[i] = coef * S[i];
}

extern "C" void kernel_launch(void* const* d_in, const int* in_sizes, int n_in,
                              void* d_out, int out_size, void* d_ws, size_t ws_size,
                              hipStream_t stream)
{
    const float* X = (const float*)d_in[0];
    const float* W = (const float*)d_in[1];
    float* ws = (float*)d_ws;
    float* XT = ws;                          // 1,179,648 floats (4.7 MB)
    float* N2 = XT + Rn * Bn * CIn;          // 4 floats
    float* PT = N2 + 4;                      // PSEG*CBO = 491,520
    float* PL = PT + PSEG * CBO;             // PSEG*CBO
    float* S  = PL + PSEG * CBO;             // 3*CBO

    hipMemsetAsync(N2, 0, 16, stream);       // zero n^2 accumulators only

    transpose_x<<<Rn, 256, 0, stream>>>(X, XT);
    pass_kernel<1><<<480, 256, 0, stream>>>(XT, W, S, N2, PT, PL);
    combine_kernel<1><<<80, 256, 0, stream>>>(PT, PL, S + 0 * CBO, N2 + 0);
    pass_kernel<2><<<480, 256, 0, stream>>>(XT, W, S, N2, PT, PL);
    combine_kernel<2><<<80, 256, 0, stream>>>(PT, PL, S + 1 * CBO, N2 + 1);
    pass_kernel<3><<<480, 256, 0, stream>>>(XT, W, S, N2, PT, PL);
    combine_kernel<3><<<80, 256, 0, stream>>>(PT, PL, S + 2 * CBO, N2 + 2);
    final_kernel<<<80, 256, 0, stream>>>(S + 2 * CBO, N2 + 2, (float*)d_out);
}